// Round 7
// baseline (500.272 us; speedup 1.0000x reference)
//
#include <hip/hip_runtime.h>
#include <hip/hip_bf16.h>
#include <stdint.h>

#define MEM_DIM 128
#define MSG_DIM 256
#define KTOT    384          // MSG_DIM + MEM_DIM
#define BM      64           // update rows per block
#define BK      32           // K elements per staged B slice
#define NBROW   384          // B rows staged per slice (3 gates x 128)

typedef __attribute__((ext_vector_type(8))) __bf16 bf16x8;
typedef __attribute__((ext_vector_type(4))) float  f32x4;

union B8u { uint32_t u[4]; bf16x8 v; };

__device__ __forceinline__ uint32_t cvt_pk(float lo, float hi) {
    uint32_t r;
    asm("v_cvt_pk_bf16_f32 %0, %1, %2" : "=v"(r) : "v"(lo), "v"(hi));
    return r;
}

__device__ __forceinline__ bf16x8 load_cvt8(const float* __restrict__ p) {
    f32x4 a = *(const f32x4*)p;
    f32x4 b = *(const f32x4*)(p + 4);
    B8u r;
    r.u[0] = cvt_pk(a.x, a.y);
    r.u[1] = cvt_pk(a.z, a.w);
    r.u[2] = cvt_pk(b.x, b.y);
    r.u[3] = cvt_pk(b.z, b.w);
    return r.v;
}

__device__ __forceinline__ float sigm(float x) {
    return __builtin_amdgcn_rcpf(1.0f + __expf(-x));
}
__device__ __forceinline__ float tanh_fast(float x) {
    return 1.0f - 2.0f * __builtin_amdgcn_rcpf(1.0f + __expf(2.0f * x));
}

// ------------------------------------------------------------- bitmap kernels
__global__ void bm_zero_kernel(uint32_t* __restrict__ bm, int nwords) {
    int i = blockIdx.x * 256 + threadIdx.x;
    if (i < nwords) bm[i] = 0;
}
__global__ void bm_set_kernel(const int* __restrict__ ids, uint32_t* __restrict__ bm, int U) {
    int i = blockIdx.x * 256 + threadIdx.x;
    if (i < U) {
        int id = ids[i];
        atomicOr(&bm[id >> 5], 1u << (id & 31));
    }
}

// ------------------------------------------------------- weight bf16 convert
__global__ void wconv_kernel(const float* __restrict__ wih,
                             const float* __restrict__ whh,
                             __hip_bfloat16* __restrict__ out) {
    int i = blockIdx.x * 256 + threadIdx.x;
    const int NIH = 3 * MEM_DIM * MSG_DIM;   // 98304
    const int NHH = 3 * MEM_DIM * MEM_DIM;   // 49152
    if (i < NIH)            out[i] = __float2bfloat16(wih[i]);
    else if (i < NIH + NHH) out[i] = __float2bfloat16(whh[i - NIH]);
}

// fallback full copy (no workspace for bitmap)
__global__ void copy_all_kernel(const f32x4* __restrict__ mem,
                                const f32x4* __restrict__ lu,
                                f32x4* __restrict__ out,
                                int n_mem4, int n_tot4) {
    int stride = gridDim.x * blockDim.x;
    for (int i = blockIdx.x * blockDim.x + threadIdx.x; i < n_tot4; i += stride) {
        f32x4 v = (i < n_mem4) ? mem[i]
                               : __builtin_nontemporal_load(&lu[i - n_mem4]);
        __builtin_nontemporal_store(v, &out[i]);
    }
}

// ------------------------------------------------------------- fused GRU+copy
// LDS: At[64][384] bf16 (x||h, XOR-swizzled), Bt[384][32] bf16 per K-slice.
// 512 threads = 8 waves; wave w owns output cols w*16..w*16+15 for all 3
// quantities. Phase X (ks 0..7): W_ih, q2 -> acc[.][2] (i_n); Phase H
// (ks 8..11): W_hh, q2 -> acc[.][3] (h_n). Bt staging pipelined through regs.
// After the tile loop, blocks grid-stride the bitmap-skip passthrough copy.
__device__ __forceinline__ int at_addr(int row, int kbyte) {
    return (row * (KTOT * 2) + kbyte) ^ ((row & 7) << 4);
}
__device__ __forceinline__ int bt_addr(int lr, int kbyte) {
    return (lr * (BK * 2) + kbyte) ^ ((lr & 7) << 4);
}

template<bool PRE, bool COPY>
__global__ __launch_bounds__(512)
void gru_fused_kernel(const float* __restrict__ memory,
                      const int*   __restrict__ ids,
                      const float* __restrict__ msgs,
                      const float* __restrict__ ts,
                      const float* __restrict__ Wih,
                      const float* __restrict__ Whh,
                      const float* __restrict__ bih,
                      const float* __restrict__ bhh,
                      const __hip_bfloat16* __restrict__ WihB,
                      const __hip_bfloat16* __restrict__ WhhB,
                      const uint32_t* __restrict__ bm,
                      const float* __restrict__ last_update,
                      float* __restrict__ out_mem,
                      float* __restrict__ out_lu,
                      int U, int ntiles, int NN) {
    __shared__ __align__(16) char At[BM * KTOT * 2];     // 49152 B
    __shared__ __align__(16) char Bt[NBROW * BK * 2];    // 24576 B

    const int tid  = threadIdx.x;
    const int w    = tid >> 6;
    const int lane = tid & 63;
    const int lq   = lane & 15;
    const int lk   = lane >> 4;

    // this lane's output column + biases (tile-invariant)
    const int c = w * 16 + lq;
    const float br  = bih[c] + bhh[c];
    const float bz  = bih[MEM_DIM + c] + bhh[MEM_DIM + c];
    const float bin = bih[2 * MEM_DIM + c];
    const float bhn = bhh[2 * MEM_DIM + c];

    // B-slice staging map: 1536 chunks of 16B; thread t handles chunks
    // {t, t+512, t+1024}; chunk -> row=chunk>>2, seg=chunk&3 (coalesced).
    const f32x4 z4 = {0.f, 0.f, 0.f, 0.f};

    #pragma unroll 1
    for (int t = blockIdx.x; t < ntiles; t += gridDim.x) {
        const int rb = t * BM;

        bf16x8 pre[3];
        // issue slice-0 loads early (overlap At staging)
        #pragma unroll
        for (int k = 0; k < 3; ++k) {
            int chunk = tid + k * 512;
            int row = chunk >> 2, seg = chunk & 3;
            if (PRE) pre[k] = *(const bf16x8*)(WihB + row * MSG_DIM + seg * 8);
            else     pre[k] = load_cvt8(Wih + (size_t)row * MSG_DIM + seg * 8);
        }

        __syncthreads();   // previous tile's epilogue done; At reusable

        // ---- stage At: x part (512 threads, 8 segs/row)
        {
            int r = tid >> 3, seg = tid & 7;
            int rA = rb + r; if (rA >= U) rA = U - 1;
            const float* xp = msgs + (size_t)rA * MSG_DIM + seg * 32;
            #pragma unroll
            for (int i = 0; i < 4; ++i)
                *(bf16x8*)(At + at_addr(r, seg * 64 + i * 16)) = load_cvt8(xp + i * 8);
        }
        // ---- stage At: h part (512 threads, 8 units/row)
        {
            int r = tid >> 3, u = tid & 7;
            int rA = rb + r; if (rA >= U) rA = U - 1;
            const float* hp = memory + (size_t)ids[rA] * MEM_DIM + u * 16;
            *(bf16x8*)(At + at_addr(r, 512 + u * 32))      = load_cvt8(hp);
            *(bf16x8*)(At + at_addr(r, 512 + u * 32 + 16)) = load_cvt8(hp + 8);
        }
        // ---- timestamp scatter
        if (tid < BM) {
            int r = rb + tid;
            if (r < U) out_lu[ids[r]] = ts[r];
        }

        f32x4 acc[4][4];
        #pragma unroll
        for (int m = 0; m < 4; ++m)
            #pragma unroll
            for (int q = 0; q < 4; ++q) acc[m][q] = z4;

        // ---------------- phase X: ks 0..7 (W_ih, K=256)
        #pragma unroll 1
        for (int ks = 0; ks < 8; ++ks) {
            __syncthreads();                 // Bt free (prev MFMA done) / At staged
            #pragma unroll
            for (int k = 0; k < 3; ++k) {    // ds_write slice (waits vmcnt)
                int chunk = tid + k * 512;
                int row = chunk >> 2, seg = chunk & 3;
                *(bf16x8*)(Bt + bt_addr(row, seg * 16)) = pre[k];
            }
            __syncthreads();                 // Bt ready
            {   // issue next-slice loads (overlap MFMA): ks+1; slice 8 = H slice 0
                const bool nx = (ks + 1 < 8);
                const int ksl = nx ? (ks + 1) : 0;
                #pragma unroll
                for (int k = 0; k < 3; ++k) {
                    int chunk = tid + k * 512;
                    int row = chunk >> 2, seg = chunk & 3;
                    if (PRE) pre[k] = nx ? *(const bf16x8*)(WihB + row * MSG_DIM + ksl * BK + seg * 8)
                                         : *(const bf16x8*)(WhhB + row * MEM_DIM + seg * 8);
                    else     pre[k] = nx ? load_cvt8(Wih + (size_t)row * MSG_DIM + ksl * BK + seg * 8)
                                         : load_cvt8(Whh + (size_t)row * MEM_DIM + seg * 8);
                }
            }
            bf16x8 af[4];
            #pragma unroll
            for (int m = 0; m < 4; ++m)
                af[m] = *(const bf16x8*)(At + at_addr(m * 16 + lq, ks * 64 + lk * 16));
            #pragma unroll
            for (int q = 0; q < 3; ++q) {
                bf16x8 bv = *(const bf16x8*)(Bt + bt_addr(q * 128 + w * 16 + lq, lk * 16));
                #pragma unroll
                for (int m = 0; m < 4; ++m)
                    acc[m][q] = __builtin_amdgcn_mfma_f32_16x16x32_bf16(af[m], bv, acc[m][q], 0, 0, 0);
            }
        }
        // ---------------- phase H: ks 8..11 (W_hh, K=128)
        #pragma unroll 1
        for (int ks = 8; ks < 12; ++ks) {
            __syncthreads();
            #pragma unroll
            for (int k = 0; k < 3; ++k) {
                int chunk = tid + k * 512;
                int row = chunk >> 2, seg = chunk & 3;
                *(bf16x8*)(Bt + bt_addr(row, seg * 16)) = pre[k];
            }
            __syncthreads();
            if (ks < 11) {
                const int ksl = ks + 1 - 8;
                #pragma unroll
                for (int k = 0; k < 3; ++k) {
                    int chunk = tid + k * 512;
                    int row = chunk >> 2, seg = chunk & 3;
                    if (PRE) pre[k] = *(const bf16x8*)(WhhB + row * MEM_DIM + ksl * BK + seg * 8);
                    else     pre[k] = load_cvt8(Whh + (size_t)row * MEM_DIM + ksl * BK + seg * 8);
                }
            }
            bf16x8 af[4];
            #pragma unroll
            for (int m = 0; m < 4; ++m)
                af[m] = *(const bf16x8*)(At + at_addr(m * 16 + lq, ks * 64 + lk * 16));
            {
                bf16x8 bv = *(const bf16x8*)(Bt + bt_addr(0 * 128 + w * 16 + lq, lk * 16));
                #pragma unroll
                for (int m = 0; m < 4; ++m)
                    acc[m][0] = __builtin_amdgcn_mfma_f32_16x16x32_bf16(af[m], bv, acc[m][0], 0, 0, 0);
            }
            {
                bf16x8 bv = *(const bf16x8*)(Bt + bt_addr(1 * 128 + w * 16 + lq, lk * 16));
                #pragma unroll
                for (int m = 0; m < 4; ++m)
                    acc[m][1] = __builtin_amdgcn_mfma_f32_16x16x32_bf16(af[m], bv, acc[m][1], 0, 0, 0);
            }
            {
                bf16x8 bv = *(const bf16x8*)(Bt + bt_addr(2 * 128 + w * 16 + lq, lk * 16));
                #pragma unroll
                for (int m = 0; m < 4; ++m)
                    acc[m][3] = __builtin_amdgcn_mfma_f32_16x16x32_bf16(af[m], bv, acc[m][3], 0, 0, 0);
            }
        }

        // ---- epilogue: gate math + scatter (h_old read back from At)
        #pragma unroll
        for (int m = 0; m < 4; ++m) {
            #pragma unroll
            for (int j = 0; j < 4; ++j) {
                int row = m * 16 + lk * 4 + j;
                int r = rb + row;
                if (r < U) {
                    int id = ids[r];
                    float hold = __bfloat162float(
                        *(const __hip_bfloat16*)(At + at_addr(row, 512 + c * 2)));
                    float rg = sigm(acc[m][0][j] + br);
                    float zg = sigm(acc[m][1][j] + bz);
                    float ng = tanh_fast(acc[m][2][j] + bin + rg * (acc[m][3][j] + bhn));
                    out_mem[(size_t)id * MEM_DIM + c] = (1.0f - zg) * ng + zg * hold;
                }
            }
        }
    }

    // ---------------- passthrough copy (bitmap-skip), grid-strided
    if (COPY) {
        const int64_t n_mem_chunks = (int64_t)NN * 32;   // 512 B rows / 16 B
        const int64_t total = n_mem_chunks + NN;
        const int64_t stride = (int64_t)gridDim.x * blockDim.x;
        const f32x4* memv = (const f32x4*)memory;
        f32x4* outv = (f32x4*)out_mem;
        for (int64_t i = (int64_t)blockIdx.x * blockDim.x + tid; i < total; i += stride) {
            if (i < n_mem_chunks) {
                int row = (int)(i >> 5);
                if (!((bm[row >> 5] >> (row & 31)) & 1u)) {
                    f32x4 v = __builtin_nontemporal_load(&memv[i]);
                    __builtin_nontemporal_store(v, &outv[i]);
                }
            } else {
                int node = (int)(i - n_mem_chunks);
                if (!((bm[node >> 5] >> (node & 31)) & 1u))
                    out_lu[node] = last_update[node];
            }
        }
    }
}

// ------------------------------------------------------------------- launcher
extern "C" void kernel_launch(void* const* d_in, const int* in_sizes, int n_in,
                              void* d_out, int out_size, void* d_ws, size_t ws_size,
                              hipStream_t stream) {
    const float* memory      = (const float*)d_in[0];
    const float* last_update = (const float*)d_in[1];
    const int*   ids         = (const int*)  d_in[2];
    const float* msgs        = (const float*)d_in[3];
    const float* ts          = (const float*)d_in[4];
    const float* Wih         = (const float*)d_in[5];
    const float* Whh         = (const float*)d_in[6];
    const float* bih         = (const float*)d_in[7];
    const float* bhh         = (const float*)d_in[8];

    const int NN = in_sizes[1];          // 1,000,000 nodes
    const int U  = in_sizes[2];          // 200,000 updates

    float* out_mem = (float*)d_out;
    float* out_lu  = out_mem + (size_t)NN * MEM_DIM;

    const int NIH = 3 * MEM_DIM * MSG_DIM;                    // 98304
    const int NHH = 3 * MEM_DIM * MEM_DIM;                    // 49152
    const size_t WBYTES  = (size_t)(NIH + NHH) * sizeof(__hip_bfloat16);  // 294912
    const size_t BM_OFF  = (WBYTES + 255) & ~(size_t)255;
    const int    BMWORDS = (NN + 31) / 32;
    const int    ntiles  = (U + BM - 1) / BM;
    const int    GRID    = 512;                               // 2 blocks/CU

    if (ws_size >= BM_OFF + (size_t)BMWORDS * 4) {
        __hip_bfloat16* wb = (__hip_bfloat16*)d_ws;
        uint32_t* bm = (uint32_t*)((char*)d_ws + BM_OFF);

        wconv_kernel<<<(NIH + NHH + 255) / 256, 256, 0, stream>>>(Wih, Whh, wb);
        bm_zero_kernel<<<(BMWORDS + 255) / 256, 256, 0, stream>>>(bm, BMWORDS);
        bm_set_kernel<<<(U + 255) / 256, 256, 0, stream>>>(ids, bm, U);

        gru_fused_kernel<true, true><<<GRID, 512, 0, stream>>>(
            memory, ids, msgs, ts, Wih, Whh, bih, bhh,
            wb, wb + NIH, bm, last_update, out_mem, out_lu, U, ntiles, NN);
    } else {
        int n_mem4 = NN * MEM_DIM / 4;
        int n_tot4 = n_mem4 + NN / 4;
        copy_all_kernel<<<8192, 256, 0, stream>>>((const f32x4*)memory,
                                                  (const f32x4*)last_update,
                                                  (f32x4*)d_out, n_mem4, n_tot4);
        gru_fused_kernel<false, false><<<GRID, 512, 0, stream>>>(
            memory, ids, msgs, ts, Wih, Whh, bih, bhh,
            nullptr, nullptr, nullptr, last_update, out_mem, out_lu, U, ntiles, NN);
    }
}

// Round 8
// 353.402 us; speedup vs baseline: 1.4156x; 1.4156x over previous
//
#include <hip/hip_runtime.h>
#include <hip/hip_bf16.h>
#include <stdint.h>

#define MEM_DIM 128
#define MSG_DIM 256
#define KTOT    384          // MSG_DIM + MEM_DIM
#define BM      64           // update rows per block

typedef __attribute__((ext_vector_type(8))) __bf16 bf16x8;
typedef __attribute__((ext_vector_type(4))) float  f32x4;

union B8u { uint32_t u[4]; bf16x8 v; };

__device__ __forceinline__ uint32_t cvt_pk(float lo, float hi) {
    uint32_t r;
    asm("v_cvt_pk_bf16_f32 %0, %1, %2" : "=v"(r) : "v"(lo), "v"(hi));
    return r;
}

__device__ __forceinline__ bf16x8 load_cvt8(const float* __restrict__ p) {
    f32x4 a = *(const f32x4*)p;
    f32x4 b = *(const f32x4*)(p + 4);
    B8u r;
    r.u[0] = cvt_pk(a.x, a.y);
    r.u[1] = cvt_pk(a.z, a.w);
    r.u[2] = cvt_pk(b.x, b.y);
    r.u[3] = cvt_pk(b.z, b.w);
    return r.v;
}

__device__ __forceinline__ float sigm(float x) {
    return __builtin_amdgcn_rcpf(1.0f + __expf(-x));
}
__device__ __forceinline__ float tanh_fast(float x) {
    return 1.0f - 2.0f * __builtin_amdgcn_rcpf(1.0f + __expf(2.0f * x));
}

// ------------------------------------------------------------- bitmap kernels
__global__ void bm_zero_kernel(uint32_t* __restrict__ bm, int nwords) {
    int i = blockIdx.x * 256 + threadIdx.x;
    if (i < nwords) bm[i] = 0;
}
__global__ void bm_set_kernel(const int* __restrict__ ids, uint32_t* __restrict__ bm, int U) {
    int i = blockIdx.x * 256 + threadIdx.x;
    if (i < U) {
        int id = ids[i];
        atomicOr(&bm[id >> 5], 1u << (id & 31));
    }
}

// ------------------------------------------------------- weight bf16 convert
__global__ void wconv_kernel(const float* __restrict__ wih,
                             const float* __restrict__ whh,
                             __hip_bfloat16* __restrict__ out) {
    int i = blockIdx.x * 256 + threadIdx.x;
    const int NIH = 3 * MEM_DIM * MSG_DIM;   // 98304
    const int NHH = 3 * MEM_DIM * MEM_DIM;   // 49152
    if (i < NIH)            out[i] = __float2bfloat16(wih[i]);
    else if (i < NIH + NHH) out[i] = __float2bfloat16(whh[i - NIH]);
}

// ----------------------------------------------- copy kernel (skips updated)
__global__ void copy_skip_kernel(const f32x4* __restrict__ mem,
                                 const float* __restrict__ lu,
                                 f32x4* __restrict__ outm,
                                 float* __restrict__ outlu,
                                 const uint32_t* __restrict__ bm,
                                 int NN) {
    const int64_t n_mem_chunks = (int64_t)NN * 32;   // 512 B rows / 16 B
    const int64_t total = n_mem_chunks + NN;
    const int64_t stride = (int64_t)gridDim.x * blockDim.x;
    for (int64_t i = (int64_t)blockIdx.x * blockDim.x + threadIdx.x; i < total; i += stride) {
        if (i < n_mem_chunks) {
            int row = (int)(i >> 5);
            if (!((bm[row >> 5] >> (row & 31)) & 1u)) {
                f32x4 v = __builtin_nontemporal_load(&mem[i]);
                __builtin_nontemporal_store(v, &outm[i]);
            }
        } else {
            int node = (int)(i - n_mem_chunks);
            if (!((bm[node >> 5] >> (node & 31)) & 1u))
                outlu[node] = lu[node];
        }
    }
}

// fallback full copy (no workspace for bitmap)
__global__ void copy_all_kernel(const f32x4* __restrict__ mem,
                                const f32x4* __restrict__ lu,
                                f32x4* __restrict__ out,
                                int n_mem4, int n_tot4) {
    int stride = gridDim.x * blockDim.x;
    for (int i = blockIdx.x * blockDim.x + threadIdx.x; i < n_tot4; i += stride) {
        f32x4 v = (i < n_mem4) ? mem[i]
                               : __builtin_nontemporal_load(&lu[i - n_mem4]);
        __builtin_nontemporal_store(v, &out[i]);
    }
}

// ---------------------------------------------------------------- stream GRU
// Block: 512 threads = 8 waves, BM=64 rows. At[64][384] bf16 in LDS (staged
// once, XOR-swizzled). B fragments stream straight from global (L2-resident
// weights) to MFMA — no Bt LDS, no per-K-step barriers. Wave w owns output
// cols w*16..w*16+15; acc[4 Mtiles][4 quantities] = 64 VGPRs.
__device__ __forceinline__ int at_addr(int row, int kbyte) {
    return (row * (KTOT * 2) + kbyte) ^ ((row & 7) << 4);
}

template<bool PRE>
__global__ __launch_bounds__(512, 4)
void gru_stream_kernel(const float* __restrict__ memory,
                       const int*   __restrict__ ids,
                       const float* __restrict__ msgs,
                       const float* __restrict__ ts,
                       const float* __restrict__ Wih,
                       const float* __restrict__ Whh,
                       const float* __restrict__ bih,
                       const float* __restrict__ bhh,
                       const __hip_bfloat16* __restrict__ WihB,  // [384][256]
                       const __hip_bfloat16* __restrict__ WhhB,  // [384][128]
                       float* __restrict__ out_mem,
                       float* __restrict__ out_lu,
                       int U) {
    __shared__ __align__(16) char At[BM * KTOT * 2];   // 49152 B

    const int tid  = threadIdx.x;
    const int w    = tid >> 6;
    const int lane = tid & 63;
    const int lq   = lane & 15;
    const int lk   = lane >> 4;
    const int rb   = blockIdx.x * BM;

    // ---- timestamp scatter
    if (tid < BM) {
        int r = rb + tid;
        if (r < U) out_lu[ids[r]] = ts[r];
    }

    // ---- stage At: x part (512 threads, 8 segs of 32 f32 per row)
    {
        int r = tid >> 3, seg = tid & 7;
        int rA = rb + r; if (rA >= U) rA = U - 1;
        const float* xp = msgs + (size_t)rA * MSG_DIM + seg * 32;
        #pragma unroll
        for (int i = 0; i < 4; ++i)
            *(bf16x8*)(At + at_addr(r, seg * 64 + i * 16)) = load_cvt8(xp + i * 8);
    }
    // ---- stage At: h part (512 threads, 8 units of 16 f32 per row)
    {
        int r = tid >> 3, u = tid & 7;
        int rA = rb + r; if (rA >= U) rA = U - 1;
        const float* hp = memory + (size_t)ids[rA] * MEM_DIM + u * 16;
        *(bf16x8*)(At + at_addr(r, 512 + u * 32))      = load_cvt8(hp);
        *(bf16x8*)(At + at_addr(r, 512 + u * 32 + 16)) = load_cvt8(hp + 8);
    }

    // this lane's output column + biases
    const int c = w * 16 + lq;
    const float br  = bih[c] + bhh[c];
    const float bz  = bih[MEM_DIM + c] + bhh[MEM_DIM + c];
    const float bin = bih[2 * MEM_DIM + c];
    const float bhn = bhh[2 * MEM_DIM + c];

    // per-lane weight base pointers (loop-invariant voffset part)
    const __hip_bfloat16* wih_l = WihB + c * MSG_DIM + lk * 8;
    const __hip_bfloat16* whh_l = WhhB + c * MEM_DIM + lk * 8;
    const float* wih_f = Wih + c * MSG_DIM + lk * 8;
    const float* whh_f = Whh + c * MEM_DIM + lk * 8;

    const f32x4 z4 = {0.f, 0.f, 0.f, 0.f};
    f32x4 acc[4][4];
    #pragma unroll
    for (int m = 0; m < 4; ++m)
        #pragma unroll
        for (int q = 0; q < 4; ++q) acc[m][q] = z4;

    __syncthreads();   // At ready

    // ---------------- phase X: W_ih, K=256, 8 k-steps, gates r,z,i_n
    #pragma unroll 1
    for (int ks = 0; ks < 8; ++ks) {
        bf16x8 bv0, bv1, bv2;
        if (PRE) {
            bv0 = *(const bf16x8*)(wih_l + 0 * 128 * MSG_DIM + ks * 32);
            bv1 = *(const bf16x8*)(wih_l + 1 * 128 * MSG_DIM + ks * 32);
            bv2 = *(const bf16x8*)(wih_l + 2 * 128 * MSG_DIM + ks * 32);
        } else {
            bv0 = load_cvt8(wih_f + 0 * 128 * MSG_DIM + ks * 32);
            bv1 = load_cvt8(wih_f + 1 * 128 * MSG_DIM + ks * 32);
            bv2 = load_cvt8(wih_f + 2 * 128 * MSG_DIM + ks * 32);
        }
        bf16x8 af[4];
        #pragma unroll
        for (int m = 0; m < 4; ++m)
            af[m] = *(const bf16x8*)(At + at_addr(m * 16 + lq, ks * 64 + lk * 16));
        #pragma unroll
        for (int m = 0; m < 4; ++m)
            acc[m][0] = __builtin_amdgcn_mfma_f32_16x16x32_bf16(af[m], bv0, acc[m][0], 0, 0, 0);
        #pragma unroll
        for (int m = 0; m < 4; ++m)
            acc[m][1] = __builtin_amdgcn_mfma_f32_16x16x32_bf16(af[m], bv1, acc[m][1], 0, 0, 0);
        #pragma unroll
        for (int m = 0; m < 4; ++m)
            acc[m][2] = __builtin_amdgcn_mfma_f32_16x16x32_bf16(af[m], bv2, acc[m][2], 0, 0, 0);
    }
    // ---------------- phase H: W_hh, K=128, 4 k-steps, gates r,z,h_n
    #pragma unroll 1
    for (int ks = 0; ks < 4; ++ks) {
        bf16x8 bv0, bv1, bv2;
        if (PRE) {
            bv0 = *(const bf16x8*)(whh_l + 0 * 128 * MEM_DIM + ks * 32);
            bv1 = *(const bf16x8*)(whh_l + 1 * 128 * MEM_DIM + ks * 32);
            bv2 = *(const bf16x8*)(whh_l + 2 * 128 * MEM_DIM + ks * 32);
        } else {
            bv0 = load_cvt8(whh_f + 0 * 128 * MEM_DIM + ks * 32);
            bv1 = load_cvt8(whh_f + 1 * 128 * MEM_DIM + ks * 32);
            bv2 = load_cvt8(whh_f + 2 * 128 * MEM_DIM + ks * 32);
        }
        bf16x8 af[4];
        #pragma unroll
        for (int m = 0; m < 4; ++m)
            af[m] = *(const bf16x8*)(At + at_addr(m * 16 + lq, 512 + ks * 64 + lk * 16));
        #pragma unroll
        for (int m = 0; m < 4; ++m)
            acc[m][0] = __builtin_amdgcn_mfma_f32_16x16x32_bf16(af[m], bv0, acc[m][0], 0, 0, 0);
        #pragma unroll
        for (int m = 0; m < 4; ++m)
            acc[m][1] = __builtin_amdgcn_mfma_f32_16x16x32_bf16(af[m], bv1, acc[m][1], 0, 0, 0);
        #pragma unroll
        for (int m = 0; m < 4; ++m)
            acc[m][3] = __builtin_amdgcn_mfma_f32_16x16x32_bf16(af[m], bv2, acc[m][3], 0, 0, 0);
    }

    // ---- epilogue: gate math + scatter (h_old read back from At)
    #pragma unroll
    for (int m = 0; m < 4; ++m) {
        #pragma unroll
        for (int j = 0; j < 4; ++j) {
            int row = m * 16 + lk * 4 + j;
            int r = rb + row;
            if (r < U) {
                int id = ids[r];
                float hold = __bfloat162float(
                    *(const __hip_bfloat16*)(At + at_addr(row, 512 + c * 2)));
                float rg = sigm(acc[m][0][j] + br);
                float zg = sigm(acc[m][1][j] + bz);
                float ng = tanh_fast(acc[m][2][j] + bin + rg * (acc[m][3][j] + bhn));
                out_mem[(size_t)id * MEM_DIM + c] = (1.0f - zg) * ng + zg * hold;
            }
        }
    }
}

// ------------------------------------------------------------------- launcher
extern "C" void kernel_launch(void* const* d_in, const int* in_sizes, int n_in,
                              void* d_out, int out_size, void* d_ws, size_t ws_size,
                              hipStream_t stream) {
    const float* memory      = (const float*)d_in[0];
    const float* last_update = (const float*)d_in[1];
    const int*   ids         = (const int*)  d_in[2];
    const float* msgs        = (const float*)d_in[3];
    const float* ts          = (const float*)d_in[4];
    const float* Wih         = (const float*)d_in[5];
    const float* Whh         = (const float*)d_in[6];
    const float* bih         = (const float*)d_in[7];
    const float* bhh         = (const float*)d_in[8];

    const int NN = in_sizes[1];          // 1,000,000 nodes
    const int U  = in_sizes[2];          // 200,000 updates

    float* out_mem = (float*)d_out;
    float* out_lu  = out_mem + (size_t)NN * MEM_DIM;

    const int NIH = 3 * MEM_DIM * MSG_DIM;                    // 98304
    const int NHH = 3 * MEM_DIM * MEM_DIM;                    // 49152
    const size_t WBYTES  = (size_t)(NIH + NHH) * sizeof(__hip_bfloat16);  // 294912
    const size_t BM_OFF  = (WBYTES + 255) & ~(size_t)255;
    const int    BMWORDS = (NN + 31) / 32;
    const int    nblocks = (U + BM - 1) / BM;                 // 3125

    if (ws_size >= BM_OFF + (size_t)BMWORDS * 4) {
        __hip_bfloat16* wb = (__hip_bfloat16*)d_ws;
        uint32_t* bm = (uint32_t*)((char*)d_ws + BM_OFF);

        wconv_kernel<<<(NIH + NHH + 255) / 256, 256, 0, stream>>>(Wih, Whh, wb);
        bm_zero_kernel<<<(BMWORDS + 255) / 256, 256, 0, stream>>>(bm, BMWORDS);
        bm_set_kernel<<<(U + 255) / 256, 256, 0, stream>>>(ids, bm, U);

        gru_stream_kernel<true><<<nblocks, 512, 0, stream>>>(
            memory, ids, msgs, ts, Wih, Whh, bih, bhh,
            wb, wb + NIH, out_mem, out_lu, U);

        copy_skip_kernel<<<8192, 256, 0, stream>>>((const f32x4*)memory, last_update,
                                                   (f32x4*)out_mem, out_lu, bm, NN);
    } else {
        int n_mem4 = NN * MEM_DIM / 4;
        int n_tot4 = n_mem4 + NN / 4;
        copy_all_kernel<<<8192, 256, 0, stream>>>((const f32x4*)memory,
                                                  (const f32x4*)last_update,
                                                  (f32x4*)d_out, n_mem4, n_tot4);
        gru_stream_kernel<false><<<nblocks, 512, 0, stream>>>(
            memory, ids, msgs, ts, Wih, Whh, bih, bhh,
            nullptr, nullptr, out_mem, out_lu, U);
    }
}